// Round 4
// baseline (356.932 us; speedup 1.0000x reference)
//
#include <hip/hip_runtime.h>

typedef _Float16 f16;
typedef _Float16 f16x8 __attribute__((ext_vector_type(8)));
typedef _Float16 f16x4 __attribute__((ext_vector_type(4)));
typedef float    f32x4 __attribute__((ext_vector_type(4)));

#define MFMA16(a, b, c) __builtin_amdgcn_mfma_f32_16x16x32_f16((a), (b), (c), 0, 0, 0)

constexpr int T = 64;    // sequence length
constexpr int C = 384;   // n_embd
constexpr int H = 64;    // head size
constexpr float SCALE = 3.26598632371090f;  // 64 * 384^-0.5

// ---------------------------------------------------------------------------
// Pack Wk,Wq,Wv (fp32 [64][384]) into f16 MFMA-fragment order (kt-major):
//   tile2 = kt*12 + wi*4 + ht      (wi: 0=K,1=Q,2=V; combo = wi*4+ht)
//   Wp[tile2*512 + lane*8 + j] = W_wi[16*ht + (lane&15)][32*kt + 8*(lane>>4) + j]
// ---------------------------------------------------------------------------
__global__ void pack_w(const float* __restrict__ Wk, const float* __restrict__ Wq,
                       const float* __restrict__ Wv, f16* __restrict__ Wp) {
  int tid = blockIdx.x * blockDim.x + threadIdx.x;
  if (tid >= 3 * 12 * 4 * 64) return;
  int lane = tid & 63;
  int tile = tid >> 6;
  int ht = tile & 3;
  int kt = (tile >> 2) % 12;
  int wi = tile / 48;
  const float* W = (wi == 0) ? Wk : ((wi == 1) ? Wq : Wv);
  int h = 16 * ht + (lane & 15);
  int c = 32 * kt + 8 * (lane >> 4);
  const float* src = W + h * C + c;
  f16x8 v;
#pragma unroll
  for (int j = 0; j < 8; ++j) v[j] = (f16)src[j];
  int tile2 = kt * 12 + wi * 4 + ht;   // kt-major store
  *(f16x8*)(Wp + (size_t)tile2 * 512 + lane * 8) = v;
}

// ---------------------------------------------------------------------------
// Kernel A (R8): QKV projection, register-streamed x. One block per batch,
// 4 waves. Wave w owns row-tile tt=w (16 rows) and ALL 12 combos.
// NO x LDS staging, NO loop barriers: x is loaded global->VGPR through an
// explicit depth-4 ring (compiler tracks exact per-register vmcnt -> never
// over-drains, unlike global_load_lds whose LDS-aliasing forces a full
// drain, measured 29% HBM in R7). W frags double-buffered in registers
// (the R6 failure was the allocator collapsing to 48 VGPRs; the explicit
// ring + wpc/wpn + launch_bounds(256,2) makes ~190 live regs structural).
// In-flight per CU: 8 waves x 3 steps x 2 KB = 48 KB > 34 KB Little's-law
// requirement for 6.3 TB/s.
// Epilogue: wave writes COMPLETE output rows (cross-wave partial-sector
// writes caused R7's 3.5x WRITE_SIZE amplification): K/Q rows direct
// f16x4; V transposed via 8.5 KB LDS overlay (verified R7 code), one
// barrier at kernel end only.
// MFMA inputs/outputs bit-identical to verified R6 phase 1.
// ---------------------------------------------------------------------------
__global__ __launch_bounds__(256, 2) void proj_reg(
    const float* __restrict__ x, const f16* __restrict__ Wp,
    f16* __restrict__ kg, f16* __restrict__ qg, f16* __restrict__ vtg) {
  __shared__ f16 vt_lds[64][68];  // V^T overlay; pitch 68 -> <=2-way banks

  const int b = blockIdx.x;
  const int tid = threadIdx.x;
  const int w = tid >> 6;       // wave 0..3 == row-tile tt
  const int lane = tid & 63;
  const int l15 = lane & 15;
  const int g = lane >> 4;      // quad 0..3

  const f32x4 vzero = {0.0f, 0.0f, 0.0f, 0.0f};
  f32x4 acc[12];                // combo cb = 4m+ht, m: 0=K,1=Q,2=V
#pragma unroll
  for (int cb = 0; cb < 12; ++cb) acc[cb] = vzero;

  // x fragment source: row 16w+l15, col 8g (+32 per kt). Identical element
  // order to verified R6: xf[j] = x[16w+l15][32kt+8g+j].
  const float* gsrc = x + (size_t)b * T * C + (size_t)(16 * w + l15) * C + 8 * g;
  const f16* wsrc = Wp + lane * 8;

  // ---- prologue: fill depth-4 x ring (8 independent loads), Wp(kt=0) frags
  f32x4 xa[4], xb[4];
#pragma unroll
  for (int i = 0; i < 4; ++i) {
    xa[i] = *(const f32x4*)(gsrc + i * 32 + 0);
    xb[i] = *(const f32x4*)(gsrc + i * 32 + 4);
  }
  f16x8 wpc[12], wpn[12];
#pragma unroll
  for (int cb = 0; cb < 12; ++cb)
    wpc[cb] = *(const f16x8*)(wsrc + (size_t)cb * 512);

  // ---- 12 K-steps, barrier-free, fully unrolled (static ring indices)
#pragma unroll
  for (int kt = 0; kt < 12; ++kt) {
    const int sl = kt & 3;
    // consume slot kt (register-dep waitcnt, compiler-precise)
    f16x8 xf;
    {
      f32x4 A0 = xa[sl], A1 = xb[sl];
#pragma unroll
      for (int j = 0; j < 4; ++j) { xf[j] = (f16)A0[j]; xf[4 + j] = (f16)A1[j]; }
    }
    // refill slot with kt+4 (issued before MFMAs -> stays in flight)
    if (kt + 4 < 12) {
      xa[sl] = *(const f32x4*)(gsrc + (kt + 4) * 32 + 0);
      xb[sl] = *(const f32x4*)(gsrc + (kt + 4) * 32 + 4);
    }
    // prefetch next-kt W frags (L1/L2-resident, shared by resident waves)
    if (kt + 1 < 12) {
#pragma unroll
      for (int cb = 0; cb < 12; ++cb)
        wpn[cb] = *(const f16x8*)(wsrc + ((size_t)(kt + 1) * 12 + cb) * 512);
    }
#pragma unroll
    for (int cb = 0; cb < 8; ++cb)   // K,Q: D[h][t] (W as A, x as B)
      acc[cb] = MFMA16(wpc[cb], xf, acc[cb]);
#pragma unroll
    for (int cb = 8; cb < 12; ++cb)  // V: D[t][h] (x as A, W as B)
      acc[cb] = MFMA16(xf, wpc[cb], acc[cb]);
#pragma unroll
    for (int cb = 0; cb < 12; ++cb) wpc[cb] = wpn[cb];
  }

  // ---- epilogue: complete rows per wave (no cross-wave partial sectors)
  // K: D[h][t]: t = 16w+l15 (lane-fixed row), h = 16ht+4g+r. 4 back-to-back
  // f16x4 stores cover the full 128-B row.
#pragma unroll
  for (int ht = 0; ht < 4; ++ht) {
    f16x4 pd;
#pragma unroll
    for (int r = 0; r < 4; ++r) pd[r] = (f16)acc[0 + ht][r];
    *(f16x4*)(kg + ((size_t)b * 64 + 16 * w + l15) * 64 + 16 * ht + 4 * g) = pd;
  }
#pragma unroll
  for (int ht = 0; ht < 4; ++ht) {
    f16x4 pd;
#pragma unroll
    for (int r = 0; r < 4; ++r) pd[r] = (f16)acc[4 + ht][r];
    *(f16x4*)(qg + ((size_t)b * 64 + 16 * w + l15) * 64 + 16 * ht + 4 * g) = pd;
  }
  // V: D[t][h]: h = 16ht+l15, t = 16w+4g+r -> LDS transpose overlay
#pragma unroll
  for (int ht = 0; ht < 4; ++ht) {
    f16x4 pd;
#pragma unroll
    for (int r = 0; r < 4; ++r) pd[r] = (f16)acc[8 + ht][r];
    *(f16x4*)&vt_lds[16 * ht + l15][16 * w + 4 * g] = pd;
  }
  __syncthreads();
  // coalesced vT store: vtg[b][h][t], linear f16x8: idx = h*8+seg
#pragma unroll
  for (int r = 0; r < 2; ++r) {
    int idx = tid + r * 256;
    f16x8 vv = *(const f16x8*)&vt_lds[idx >> 3][(idx & 7) * 8];
    *(f16x8*)(vtg + (size_t)b * 4096 + idx * 8) = vv;
  }
}

// ---------------------------------------------------------------------------
// Kernel B (verbatim from R7, passed): attention per batch. One block per
// batch, 4 waves, 27.6 KB LDS -> 5 blocks/CU. Stages k/q/vT tiles (linear
// f16x8 global loads) into the pitch-72 LDS layout, then phases 2-4 + store
// VERBATIM from the verified fused kernel.
// ---------------------------------------------------------------------------
__global__ __launch_bounds__(256, 5) void attn64(
    const f16* __restrict__ kg, const f16* __restrict__ qg,
    const f16* __restrict__ vtg, float* __restrict__ out) {
  // pitch 72 f16 = 36 dwords; 36 % 32 = 4 -> <=2-way LDS bank aliasing (free)
  __shared__ f16 qp_lds[64][72];  // phase 2: q[t][h]; phases 3-4: P[t][s]
  __shared__ f16 k_lds[64][72];   // k[t][h]
  __shared__ f16 vT_lds[64][72];  // v^T[h][t]

  const int b = blockIdx.x;
  const int tid = threadIdx.x;
  const int w = tid >> 6;
  const int lane = tid & 63;
  const int l15 = lane & 15;
  const int g = lane >> 4;
  const int t_ = 16 * w + l15;

  // ---- stage: 6 independent 16B loads, then 6 LDS writes
  const size_t tb = (size_t)b * 4096;
  const int i0 = tid, i1 = tid + 256;
  f16x8 ka = *(const f16x8*)(kg + tb + (size_t)i0 * 8);
  f16x8 kb = *(const f16x8*)(kg + tb + (size_t)i1 * 8);
  f16x8 qa = *(const f16x8*)(qg + tb + (size_t)i0 * 8);
  f16x8 qb = *(const f16x8*)(qg + tb + (size_t)i1 * 8);
  f16x8 va = *(const f16x8*)(vtg + tb + (size_t)i0 * 8);
  f16x8 vb = *(const f16x8*)(vtg + tb + (size_t)i1 * 8);
  *(f16x8*)&k_lds[i0 >> 3][(i0 & 7) * 8] = ka;
  *(f16x8*)&k_lds[i1 >> 3][(i1 & 7) * 8] = kb;
  *(f16x8*)&qp_lds[i0 >> 3][(i0 & 7) * 8] = qa;
  *(f16x8*)&qp_lds[i1 >> 3][(i1 & 7) * 8] = qb;
  *(f16x8*)&vT_lds[i0 >> 3][(i0 & 7) * 8] = va;
  *(f16x8*)&vT_lds[i1 >> 3][(i1 & 7) * 8] = vb;
  __syncthreads();

  const f32x4 vzero = {0.0f, 0.0f, 0.0f, 0.0f};

  // ---- Phase 2: S^T = k.q^T  (lane holds column t_ of S, 16 s-entries)
  f32x4 accs[4];
#pragma unroll
  for (int i = 0; i < 4; ++i) accs[i] = vzero;
#pragma unroll
  for (int kt = 0; kt < 2; ++kt) {
    f16x8 qf = *(const f16x8*)&qp_lds[t_][32 * kt + 8 * g];
#pragma unroll
    for (int mt = 0; mt < 4; ++mt) {
      f16x8 kf = *(const f16x8*)&k_lds[16 * mt + l15][32 * kt + 8 * g];
      accs[mt] = MFMA16(kf, qf, accs[mt]);  // D[s][t]: s = 16mt+4g+r, t = t_
    }
  }

  // ---- Phase 3: causal mask + softmax over s (per column t_, fp32)
  float e[16];
  float mx = -__builtin_inff();
#pragma unroll
  for (int mt = 0; mt < 4; ++mt) {
#pragma unroll
    for (int r = 0; r < 4; ++r) {
      int s = 16 * mt + 4 * g + r;
      float lv = accs[mt][r] * SCALE;
      lv = (s <= t_) ? lv : -__builtin_inff();
      e[mt * 4 + r] = lv;
      mx = fmaxf(mx, lv);
    }
  }
  mx = fmaxf(mx, __shfl_xor(mx, 16));
  mx = fmaxf(mx, __shfl_xor(mx, 32));
  float sm = 0.0f;
#pragma unroll
  for (int i = 0; i < 16; ++i) { e[i] = __expf(e[i] - mx); sm += e[i]; }
  sm += __shfl_xor(sm, 16);
  sm += __shfl_xor(sm, 32);
  const float inv = 1.0f / sm;
  // P overwrites qp_lds rows [16w,16w+16): wave-private rows; all other
  // waves' post-barrier qp_lds reads are own-row only. No barrier needed.
#pragma unroll
  for (int mt = 0; mt < 4; ++mt) {
    f16x4 pp;
#pragma unroll
    for (int r = 0; r < 4; ++r) pp[r] = (f16)(e[mt * 4 + r] * inv);
    *(f16x4*)&qp_lds[t_][16 * mt + 4 * g] = pp;  // P[t][s], s = 16mt+4g+r
  }

  // ---- Phase 4: out^T = v^T . P^T  (A = vT, B-frag from P[t][s])
  f32x4 acco[4];
#pragma unroll
  for (int i = 0; i < 4; ++i) acco[i] = vzero;
#pragma unroll
  for (int kt = 0; kt < 2; ++kt) {
    f16x8 pf = *(const f16x8*)&qp_lds[t_][32 * kt + 8 * g];
#pragma unroll
    for (int mt = 0; mt < 4; ++mt) {
      f16x8 vf = *(const f16x8*)&vT_lds[16 * mt + l15][32 * kt + 8 * g];
      acco[mt] = MFMA16(vf, pf, acco[mt]);  // D[h][t]: h = 16mt+4g+r, t = t_
    }
  }

  // ---- store: out[b][t][h] fp32, 4 consecutive h per reg quad -> float4
  float* orow = out + ((size_t)b * T + t_) * H;
#pragma unroll
  for (int mt = 0; mt < 4; ++mt) {
    *(f32x4*)(orow + 16 * mt + 4 * g) = acco[mt];
  }
}

extern "C" void kernel_launch(void* const* d_in, const int* in_sizes, int n_in,
                              void* d_out, int out_size, void* d_ws, size_t ws_size,
                              hipStream_t stream) {
  const float* x  = (const float*)d_in[0];
  const float* Wk = (const float*)d_in[1];
  const float* Wq = (const float*)d_in[2];
  const float* Wv = (const float*)d_in[3];
  float* out = (float*)d_out;

  // workspace layout: Wp (147456 B, padded to 256 KiB) | kg | qg | vtg
  f16* Wp  = (f16*)d_ws;
  f16* kg  = (f16*)((char*)d_ws + (1 << 18));
  f16* qg  = kg + (size_t)2048 * 64 * 64;   // 16 MiB each
  f16* vtg = qg + (size_t)2048 * 64 * 64;

  pack_w<<<36, 256, 0, stream>>>(Wk, Wq, Wv, Wp);
  proj_reg<<<2048, 256, 0, stream>>>(x, Wp, kg, qg, vtg);
  attn64<<<2048, 256, 0, stream>>>(kg, qg, vtg, out);
}

// Round 5
// 297.088 us; speedup vs baseline: 1.2014x; 1.2014x over previous
//
#include <hip/hip_runtime.h>

typedef _Float16 f16;
typedef _Float16 f16x8 __attribute__((ext_vector_type(8)));
typedef _Float16 f16x4 __attribute__((ext_vector_type(4)));
typedef float    f32x4 __attribute__((ext_vector_type(4)));

#define MFMA16(a, b, c) __builtin_amdgcn_mfma_f32_16x16x32_f16((a), (b), (c), 0, 0, 0)

constexpr int T = 64;    // sequence length
constexpr int C = 384;   // n_embd
constexpr int H = 64;    // head size
constexpr float SCALE = 3.26598632371090f;  // 64 * 384^-0.5

// async global->LDS, 16B per lane; LDS dest = wave-uniform base + lane*16
__device__ __forceinline__ void load_lds16(const float* g, float* l) {
  __builtin_amdgcn_global_load_lds(
      (const __attribute__((address_space(1))) void*)g,
      (__attribute__((address_space(3))) void*)l, 16, 0, 0);
}

// ---------------------------------------------------------------------------
// Pack Wk,Wq,Wv (fp32 [64][384]) into f16 MFMA-fragment order (ktp-major):
//   tile2 = ktp*12 + wi*4 + ht      (ktp = K/32 index 0..11; wi: 0=K,1=Q,2=V)
//   Wp[tile2*512 + lane*8 + j] = W_wi[16*ht + (lane&15)][32*ktp + 8*(lane>>4) + j]
// ---------------------------------------------------------------------------
__global__ void pack_w(const float* __restrict__ Wk, const float* __restrict__ Wq,
                       const float* __restrict__ Wv, f16* __restrict__ Wp) {
  int tid = blockIdx.x * blockDim.x + threadIdx.x;
  if (tid >= 3 * 12 * 4 * 64) return;
  int lane = tid & 63;
  int tile = tid >> 6;
  int ht = tile & 3;
  int kt = (tile >> 2) % 12;
  int wi = tile / 48;
  const float* W = (wi == 0) ? Wk : ((wi == 1) ? Wq : Wv);
  int h = 16 * ht + (lane & 15);
  int c = 32 * kt + 8 * (lane >> 4);
  const float* src = W + h * C + c;
  f16x8 v;
#pragma unroll
  for (int j = 0; j < 8; ++j) v[j] = (f16)src[j];
  int tile2 = kt * 12 + wi * 4 + ht;   // ktp-major store
  *(f16x8*)(Wp + (size_t)tile2 * 512 + lane * 8) = v;
}

// ---------------------------------------------------------------------------
// Fused head kernel (R9). One block per batch, 4 waves. Back to the verified
// R0/R5 fused structure (best measured: ~97 us), with the phase-1 staging
// re-engineered for memory-level parallelism:
//   - BK=64 chunks (16 KB, 4 DMA instrs/wave) instead of 32 (8 KB, 2 instrs)
//     -> 6 barrier periods instead of 12, 2x in-flight bytes per wave.
//   - 3 chunk buffers, depth-2 prefetch -> up to 8 DMA instrs (8 KB) in
//     flight per wave across barriers.
//   - counted vmcnt via raw asm + raw s_barrier. CRITICAL ordering fix vs
//     R5: within an iter, Wp loads are issued BEFORE the prefetch DMAs, so
//     the compiler's own register-dep wait for Wp(kt) (in-order vmcnt)
//     forces only DMA(kt) (already required) and NOT the in-flight
//     DMA(kt+1)/DMA(kt+2).
// vmcnt ledger (per-iter issue: wp(kt+1)=6 ops, then DMA(kt+2)=4 ops):
//   top of iter kt needs DMA(kt) retired. Ops issued after DMA(kt):
//   wp(kt)6 + DMA(kt+1)4 = 10 -> vmcnt(10) for kt=0..4; kt=5: only wp(5)6
//   outstanding -> vmcnt(6). Prologue order DMA(0),wp(0),DMA(1) makes
//   kt=0 fit the same vmcnt(10).
// Buffer reuse: DMA(kt+2) (issued after barrier kt) targets buf (kt-1)%3,
// whose readers (iter kt-1) consumed their ds_reads via cvts before
// reaching barrier kt. Attention LDS (27.6 KB) overlays staging bufs 0/1
// (time-disjoint: all DMAs retired by top of iter 5; overlay written after
// the post-loop barrier). Total LDS 48 KB, 3 blocks/CU (= the observed
// occupancy pin anyway).
// Phases 2-4 + store verbatim from the verified kernel.
// ---------------------------------------------------------------------------
__global__ __launch_bounds__(256, 3) void head_fused(
    const float* __restrict__ x, const f16* __restrict__ Wp,
    float* __restrict__ out) {
  __shared__ __attribute__((aligned(16))) char smem[49152];
  float* xcf = (float*)smem;                    // [3][4096] floats, 48 KB
  typedef f16 row72[72];                        // pitch 72: <=2-way banks
  row72* qp_lds = (row72*)smem;                 // [64][72] overlay @0
  row72* k_lds  = (row72*)(smem + 9216);        // [64][72] overlay @9216
  row72* vT_lds = (row72*)(smem + 18432);       // [64][72] overlay @18432

  const int b = blockIdx.x;
  const int tid = threadIdx.x;
  const int w = tid >> 6;       // wave 0..3
  const int lane = tid & 63;
  const int l15 = lane & 15;
  const int g = lane >> 4;      // quad 0..3
  const int t_ = 16 * w + l15;  // this lane's t for phases 2-4

  const f32x4 vzero = {0.0f, 0.0f, 0.0f, 0.0f};
  f32x4 acc[3][4];              // combo c = 3w+c, row-tile tt
#pragma unroll
  for (int c = 0; c < 3; ++c)
#pragma unroll
    for (int tt = 0; tt < 4; ++tt) acc[c][tt] = vzero;

  const f16* wp_base[3];
  bool isV[3];
#pragma unroll
  for (int c = 0; c < 3; ++c) {
    int combo = 3 * w + c;
    wp_base[c] = Wp + (size_t)combo * 512 + lane * 8;  // + ktp*6144 per K/32
    isV[c] = (combo >= 8);
  }

  const float* xbase = x + (size_t)b * T * C;
  // Wave w stages rows [16w,16w+16). Verified fragment-interleave per
  // 32-col subchunk: xcf[buf*4096 + kh*2048 + (2tt+hf)*256 + lane*4 + j]
  //   = x[16tt+(lane&15)][kt*64 + kh*32 + (lane>>4)*8 + hf*4 + j]
  const float* gsrc = xbase + (size_t)(16 * w + l15) * C + 8 * g;

  // ---- prologue: DMA(chunk0); wp(0); DMA(chunk1)  [ledger order]
#pragma unroll
  for (int kh = 0; kh < 2; ++kh)
#pragma unroll
    for (int hf = 0; hf < 2; ++hf)
      load_lds16(gsrc + kh * 32 + hf * 4, &xcf[0 * 4096 + kh * 2048 + (2 * w + hf) * 256]);
  f16x8 wpc[3][2], wpn[3][2];
#pragma unroll
  for (int c = 0; c < 3; ++c)
#pragma unroll
    for (int kh = 0; kh < 2; ++kh)
      wpc[c][kh] = *(const f16x8*)(wp_base[c] + (size_t)(0 * 2 + kh) * 6144);
  __builtin_amdgcn_sched_barrier(0);
#pragma unroll
  for (int kh = 0; kh < 2; ++kh)
#pragma unroll
    for (int hf = 0; hf < 2; ++hf)
      load_lds16(gsrc + 64 + kh * 32 + hf * 4, &xcf[1 * 4096 + kh * 2048 + (2 * w + hf) * 256]);

  // ---- Phase 1: 6 K-chunks (BK=64), counted-vmcnt pipeline
#pragma unroll
  for (int kt = 0; kt < 6; ++kt) {
    const int cur = kt % 3;
    if (kt < 5) {
      asm volatile("s_waitcnt vmcnt(10)" ::: "memory");
    } else {
      asm volatile("s_waitcnt vmcnt(6)" ::: "memory");
    }
    __builtin_amdgcn_sched_barrier(0);
    __builtin_amdgcn_s_barrier();
    __builtin_amdgcn_sched_barrier(0);

    // wp(kt+1) FIRST (so its reg-dep wait never drains later DMAs)
    if (kt + 1 < 6) {
#pragma unroll
      for (int c = 0; c < 3; ++c)
#pragma unroll
        for (int kh = 0; kh < 2; ++kh)
          wpn[c][kh] = *(const f16x8*)(wp_base[c] + (size_t)((kt + 1) * 2 + kh) * 6144);
    }
    __builtin_amdgcn_sched_barrier(0);
    // DMA(kt+2) into buf (kt+2)%3
    if (kt + 2 < 6) {
      const int nb = (kt + 2) % 3;
#pragma unroll
      for (int kh = 0; kh < 2; ++kh)
#pragma unroll
        for (int hf = 0; hf < 2; ++hf)
          load_lds16(gsrc + (kt + 2) * 64 + kh * 32 + hf * 4,
                     &xcf[nb * 4096 + kh * 2048 + (2 * w + hf) * 256]);
    }
    __builtin_amdgcn_sched_barrier(0);

    // compute chunk kt: two 32-wide subchunks, verified math per subchunk
#pragma unroll
    for (int kh = 0; kh < 2; ++kh) {
      f16x8 xf[4];
#pragma unroll
      for (int tt = 0; tt < 4; ++tt) {
        f32x4 A0 = *(const f32x4*)&xcf[cur * 4096 + kh * 2048 + (2 * tt + 0) * 256 + lane * 4];
        f32x4 A1 = *(const f32x4*)&xcf[cur * 4096 + kh * 2048 + (2 * tt + 1) * 256 + lane * 4];
#pragma unroll
        for (int j = 0; j < 4; ++j) { xf[tt][j] = (f16)A0[j]; xf[tt][4 + j] = (f16)A1[j]; }
      }
#pragma unroll
      for (int c = 0; c < 3; ++c) {
        f16x8 wf = wpc[c][kh];
        if (!isV[c]) {  // K or Q: D[h][t] (W as A, x as B)
#pragma unroll
          for (int tt = 0; tt < 4; ++tt) acc[c][tt] = MFMA16(wf, xf[tt], acc[c][tt]);
        } else {        // V: D[t][h] (x as A, W as B)
#pragma unroll
          for (int tt = 0; tt < 4; ++tt) acc[c][tt] = MFMA16(xf[tt], wf, acc[c][tt]);
        }
      }
    }
#pragma unroll
    for (int c = 0; c < 3; ++c)
#pragma unroll
      for (int kh = 0; kh < 2; ++kh) wpc[c][kh] = wpn[c][kh];
  }

  // all waves done reading chunk 5 before overlay writes
  __builtin_amdgcn_s_barrier();

  // ---- Phase-1 epilogue: write q/k/vT to LDS overlay, D-layout, b64/tile.
#pragma unroll
  for (int c = 0; c < 3; ++c) {
    int combo = 3 * w + c;
    int m = combo >> 2;
    int ht = combo & 3;
#pragma unroll
    for (int tt = 0; tt < 4; ++tt) {
      f16x4 pd;
#pragma unroll
      for (int r = 0; r < 4; ++r) pd[r] = (f16)acc[c][tt][r];
      if (m == 0) {        // K: col=t (16tt+l15), row=h (16ht+4g+r)
        *(f16x4*)&k_lds[16 * tt + l15][16 * ht + 4 * g] = pd;
      } else if (m == 1) { // Q
        *(f16x4*)&qp_lds[16 * tt + l15][16 * ht + 4 * g] = pd;
      } else {             // V: col=h (16ht+l15), row=t (16tt+4g+r)
        *(f16x4*)&vT_lds[16 * ht + l15][16 * tt + 4 * g] = pd;
      }
    }
  }
  __syncthreads();

  // ---- Phase 2: S^T = k.q^T  (lane holds column t_ of S, 16 s-entries)
  f32x4 accs[4];
#pragma unroll
  for (int i = 0; i < 4; ++i) accs[i] = vzero;
#pragma unroll
  for (int kt = 0; kt < 2; ++kt) {
    f16x8 qf = *(const f16x8*)&qp_lds[t_][32 * kt + 8 * g];
#pragma unroll
    for (int mt = 0; mt < 4; ++mt) {
      f16x8 kf = *(const f16x8*)&k_lds[16 * mt + l15][32 * kt + 8 * g];
      accs[mt] = MFMA16(kf, qf, accs[mt]);  // D[s][t]: s = 16mt+4g+r, t = t_
    }
  }

  // ---- Phase 3: causal mask + softmax over s (per column t_, fp32)
  float e[16];
  float mx = -__builtin_inff();
#pragma unroll
  for (int mt = 0; mt < 4; ++mt) {
#pragma unroll
    for (int r = 0; r < 4; ++r) {
      int s = 16 * mt + 4 * g + r;
      float lv = accs[mt][r] * SCALE;
      lv = (s <= t_) ? lv : -__builtin_inff();
      e[mt * 4 + r] = lv;
      mx = fmaxf(mx, lv);
    }
  }
  mx = fmaxf(mx, __shfl_xor(mx, 16));
  mx = fmaxf(mx, __shfl_xor(mx, 32));
  float sm = 0.0f;
#pragma unroll
  for (int i = 0; i < 16; ++i) { e[i] = __expf(e[i] - mx); sm += e[i]; }
  sm += __shfl_xor(sm, 16);
  sm += __shfl_xor(sm, 32);
  const float inv = 1.0f / sm;
  // P overwrites qp_lds rows [16w,16w+16): wave-private rows; all other
  // waves' post-barrier qp_lds reads are own-row only. No barrier needed.
#pragma unroll
  for (int mt = 0; mt < 4; ++mt) {
    f16x4 pp;
#pragma unroll
    for (int r = 0; r < 4; ++r) pp[r] = (f16)(e[mt * 4 + r] * inv);
    *(f16x4*)&qp_lds[t_][16 * mt + 4 * g] = pp;  // P[t][s], s = 16mt+4g+r
  }

  // ---- Phase 4: out^T = v^T . P^T  (A = vT, B-frag from P[t][s])
  f32x4 acco[4];
#pragma unroll
  for (int i = 0; i < 4; ++i) acco[i] = vzero;
#pragma unroll
  for (int kt = 0; kt < 2; ++kt) {
    f16x8 pf = *(const f16x8*)&qp_lds[t_][32 * kt + 8 * g];
#pragma unroll
    for (int mt = 0; mt < 4; ++mt) {
      f16x8 vf = *(const f16x8*)&vT_lds[16 * mt + l15][32 * kt + 8 * g];
      acco[mt] = MFMA16(vf, pf, acco[mt]);  // D[h][t]: h = 16mt+4g+r, t = t_
    }
  }

  // ---- store: out[b][t][h] fp32, 4 consecutive h per reg quad -> float4
  float* orow = out + ((size_t)b * T + t_) * H;
#pragma unroll
  for (int mt = 0; mt < 4; ++mt) {
    *(f32x4*)(orow + 16 * mt + 4 * g) = acco[mt];
  }
}

extern "C" void kernel_launch(void* const* d_in, const int* in_sizes, int n_in,
                              void* d_out, int out_size, void* d_ws, size_t ws_size,
                              hipStream_t stream) {
  const float* x  = (const float*)d_in[0];
  const float* Wk = (const float*)d_in[1];
  const float* Wq = (const float*)d_in[2];
  const float* Wv = (const float*)d_in[3];
  float* out = (float*)d_out;
  f16* Wp = (f16*)d_ws;  // 3*12*4*64*8 f16 = 147456 B

  // Re-pack every launch: d_ws is re-poisoned before each timed call.
  pack_w<<<36, 256, 0, stream>>>(Wk, Wq, Wv, Wp);
  head_fused<<<2048, 256, 0, stream>>>(x, Wp, out);
}